// Round 10
// baseline (592.660 us; speedup 1.0000x reference)
//
#include <hip/hip_runtime.h>

using s16x8 = __attribute__((ext_vector_type(8))) short;   // 8 bf16 (4 VGPRs)
using f32x4 = __attribute__((ext_vector_type(4))) float;   // MFMA accumulator
using f32x2 = __attribute__((ext_vector_type(2))) float;   // packed fp32
typedef unsigned short ushort_t;

__device__ __forceinline__ unsigned short f2bf(float f) {
    union { float f; unsigned u; } v; v.f = f;
    unsigned u = v.u + 0x7FFFu + ((v.u >> 16) & 1u);   // round-nearest-even
    return (unsigned short)(u >> 16);
}
__device__ __forceinline__ float bf2f(unsigned short h) {
    union { unsigned u; float f; } v; v.u = ((unsigned)h) << 16;
    return v.f;
}

// block reduction: op==0 sum, op==1 max. lds >= blockDim/64 floats.
__device__ __forceinline__ float block_reduce(float v, int op, float* lds) {
    const int lane = threadIdx.x & 63;
    const int w    = threadIdx.x >> 6;
    const int nw   = blockDim.x >> 6;
#pragma unroll
    for (int off = 32; off > 0; off >>= 1) {
        float o = __shfl_down(v, off, 64);
        v = op ? fmaxf(v, o) : (v + o);
    }
    __syncthreads();
    if (lane == 0) lds[w] = v;
    __syncthreads();
    float r = lds[0];
    for (int i = 1; i < nw; i++) r = op ? fmaxf(r, lds[i]) : (r + lds[i]);
    return r;
}

__device__ __forceinline__ void load_lds16(const void* g, void* l) {
    __builtin_amdgcn_global_load_lds(
        (const __attribute__((address_space(1))) unsigned int*)g,
        (__attribute__((address_space(3))) unsigned int*)l, 16, 0, 0);
}

// ---------------------------------------------------------------------------
// fp32 -> bf16 weight conversion, all 8 weights in one dispatch
// ---------------------------------------------------------------------------
struct CvtArgs { const float* src[8]; ushort_t* dst[8]; int end[8]; };

__global__ __launch_bounds__(256)
void cvt_all(CvtArgs a)
{
    int i = blockIdx.x * 256 + threadIdx.x;
    int j = 0;
    while (j < 8 && i >= a.end[j]) j++;
    if (j >= 8) return;
    int li = i - (j ? a.end[j - 1] : 0);
    float4 v = *(const float4*)&a.src[j][(size_t)li * 4];
    ushort_t u[4] = { f2bf(v.x), f2bf(v.y), f2bf(v.z), f2bf(v.w) };
    *(uint2*)&a.dst[j][(size_t)li * 4] = *(uint2*)u;
}

// ---------------------------------------------------------------------------
// bf16 GEMM, BK=32, XOR-swizzled LDS.
//   Normal:  C[z] = act(alpha*A[z]@B[z]^T + bias), bf16 out.
//   SPLITK:  blockIdx.z = ks*zmod + zb; K-chunk [ks*ksplen,+ksplen), raw fp32
//            (alpha applied, no bias/act) to Cp + ks*pstride + usual index.
// ---------------------------------------------------------------------------
template<bool RELU, bool SPLITK>
__global__ __launch_bounds__(256, 2)
void gemm_bf16(const ushort_t* __restrict__ A, const ushort_t* __restrict__ B,
               const float* __restrict__ bias, ushort_t* __restrict__ C,
               float* __restrict__ Cp, long pstride, int ksplen, int zmod,
               int M, int N, int K, int lda, int ldb, int ldc,
               long sAz, long sBz, long sCz, long sA2, long sB2, long sC2,
               int zshift, float alpha)
{
    __shared__ ushort_t As[128 * 32];
    __shared__ ushort_t Bs[128 * 32];

    const int tid = threadIdx.x;
    int zz = blockIdx.z;
    int ks = 0, z = zz;
    if (SPLITK) { ks = zz / zmod; z = zz - ks * zmod; }
    const int z1  = z & ((1 << zshift) - 1);
    const int z2  = z >> zshift;
    const int m0  = blockIdx.x * 128;
    const int n0  = blockIdx.y * 128;

    const ushort_t* Ab = A + (size_t)z1 * sAz + (size_t)z2 * sA2 + (size_t)m0 * lda;
    const ushort_t* Bb = B + (size_t)z1 * sBz + (size_t)z2 * sB2 + (size_t)n0 * ldb;

    const int wave = tid >> 6, lane = tid & 63;
    const int wm = (wave & 1) * 64, wn = (wave >> 1) * 64;
    const int mi = lane & 15, quad = lane >> 4;

    f32x4 acc[4][4];
#pragma unroll
    for (int i = 0; i < 4; i++)
#pragma unroll
        for (int j = 0; j < 4; j++) acc[i][j] = (f32x4)0.f;

    const int r_0 = tid >> 2,           g_0 = (tid & 3) ^ ((r_0 >> 1) & 3);
    const int r_1 = (tid + 256) >> 2,   g_1 = (tid & 3) ^ ((r_1 >> 1) & 3);

    const int kbeg = SPLITK ? ks * ksplen : 0;
    const int kend = SPLITK ? kbeg + ksplen : K;

    for (int k0 = kbeg; k0 < kend; k0 += 32) {
        load_lds16(Ab + (size_t)r_0 * lda + k0 + g_0 * 8, &As[tid * 8]);
        load_lds16(Ab + (size_t)r_1 * lda + k0 + g_1 * 8, &As[(tid + 256) * 8]);
        load_lds16(Bb + (size_t)r_0 * ldb + k0 + g_0 * 8, &Bs[tid * 8]);
        load_lds16(Bb + (size_t)r_1 * ldb + k0 + g_1 * 8, &Bs[(tid + 256) * 8]);
        __syncthreads();

        s16x8 af[4], bfr[4];
#pragma unroll
        for (int t = 0; t < 4; t++) {
            int r = wm + t * 16 + mi;
            af[t] = *(const s16x8*)&As[r * 32 + ((quad ^ ((r >> 1) & 3)) * 8)];
        }
#pragma unroll
        for (int t = 0; t < 4; t++) {
            int r = wn + t * 16 + mi;
            bfr[t] = *(const s16x8*)&Bs[r * 32 + ((quad ^ ((r >> 1) & 3)) * 8)];
        }
#pragma unroll
        for (int tm = 0; tm < 4; tm++)
#pragma unroll
            for (int tn = 0; tn < 4; tn++)
                acc[tm][tn] = __builtin_amdgcn_mfma_f32_16x16x32_bf16(af[tm], bfr[tn], acc[tm][tn], 0, 0, 0);
        __syncthreads();
    }

    if (SPLITK) {
        float* Cf = Cp + (size_t)ks * pstride + (size_t)z1 * sCz + (size_t)z2 * sC2;
#pragma unroll
        for (int tn = 0; tn < 4; tn++) {
            int col = n0 + wn + tn * 16 + mi;
#pragma unroll
            for (int tm = 0; tm < 4; tm++)
#pragma unroll
                for (int r = 0; r < 4; r++) {
                    int row = m0 + wm + tm * 16 + quad * 4 + r;
                    Cf[(size_t)row * ldc + col] = acc[tm][tn][r] * alpha;
                }
        }
    } else {
#pragma unroll
        for (int tn = 0; tn < 4; tn++) {
            int col = n0 + wn + tn * 16 + mi;
            float bv = bias ? bias[col] : 0.f;
#pragma unroll
            for (int tm = 0; tm < 4; tm++) {
#pragma unroll
                for (int r = 0; r < 4; r++) {
                    int row = m0 + wm + tm * 16 + quad * 4 + r;
                    float v = acc[tm][tn][r] * alpha + bv;
                    if (RELU) v = fmaxf(v, 0.f);
                    C[(size_t)z1 * sCz + (size_t)z2 * sC2 + (size_t)row * ldc + col] = f2bf(v);
                }
            }
        }
    }
}

// sum P fp32 partials (+bias per col) [relu] -> bf16
template<bool RELU>
__global__ __launch_bounds__(256)
void sum_cvt(const float* __restrict__ parts, long pstride, int P,
             const float* __restrict__ bias, int ldc,
             ushort_t* __restrict__ out, int total4)
{
    int i = blockIdx.x * 256 + threadIdx.x;
    if (i >= total4) return;
    size_t idx = (size_t)i * 4;
    float4 s = *(const float4*)&parts[idx];
    for (int p = 1; p < P; p++) {
        float4 v = *(const float4*)&parts[(size_t)p * pstride + idx];
        s.x += v.x; s.y += v.y; s.z += v.z; s.w += v.w;
    }
    if (bias) {
        int col = (int)(idx % (size_t)ldc);
        s.x += bias[col]; s.y += bias[col + 1]; s.z += bias[col + 2]; s.w += bias[col + 3];
    }
    if (RELU) {
        s.x = fmaxf(s.x, 0.f); s.y = fmaxf(s.y, 0.f);
        s.z = fmaxf(s.z, 0.f); s.w = fmaxf(s.w, 0.f);
    }
    ushort_t u[4] = { f2bf(s.x), f2bf(s.y), f2bf(s.z), f2bf(s.w) };
    *(uint2*)&out[idx] = *(uint2*)u;
}

// fused split-K reduce + LN:  out = LN(Σ parts + bias [+ residB]) * g + beta [+ post]
// D = 1024, 256 threads, bf16 out.
__global__ __launch_bounds__(256)
void sum_ln(const float* __restrict__ parts, long pstride, int P,
            const float* __restrict__ bias, const ushort_t* __restrict__ residB,
            const ushort_t* __restrict__ post, const float* __restrict__ g,
            const float* __restrict__ beta, ushort_t* __restrict__ out)
{
    __shared__ float red[4];
    const size_t row = blockIdx.x;
    const int tid = threadIdx.x;
    float xr[4];
    float s = 0.f, ss = 0.f;
#pragma unroll
    for (int i = 0; i < 4; i++) {
        int idx = i * 256 + tid;
        float x = bias[idx];
        for (int p = 0; p < P; p++) x += parts[(size_t)p * pstride + row * 1024 + idx];
        if (residB) x += bf2f(residB[row * 1024 + idx]);
        xr[i] = x; s += x; ss = fmaf(x, x, ss);
    }
    s  = block_reduce(s, 0, red);
    ss = block_reduce(ss, 0, red);
    float mean = s * (1.f / 1024.f);
    float var  = ss * (1.f / 1024.f) - mean * mean;
    float inv  = rsqrtf(var + 1e-5f);
#pragma unroll
    for (int i = 0; i < 4; i++) {
        int idx = i * 256 + tid;
        float v = (xr[i] - mean) * inv * g[idx] + beta[idx];
        if (post) v += bf2f(post[row * 1024 + idx]);
        out[row * 1024 + idx] = f2bf(v);
    }
}

// final LN over (sum of P fp32 partials + bias + bf16 residual), D=128, fp32 out
__global__ __launch_bounds__(128)
void ln_part(const float* __restrict__ parts, long pstride, int P,
             const float* __restrict__ bias, const ushort_t* __restrict__ resid,
             const float* __restrict__ g, const float* __restrict__ beta,
             float* __restrict__ out)
{
    __shared__ float red[4];
    const int r = blockIdx.x, c = threadIdx.x;
    float x = bias[c] + bf2f(resid[r * 128 + c]);
    for (int p = 0; p < P; p++) x += parts[(size_t)p * pstride + (size_t)r * 128 + c];
    float s  = block_reduce(x, 0, red);
    float ss = block_reduce(x * x, 0, red);
    float mean = s * (1.f / 128.f);
    float var  = ss * (1.f / 128.f) - mean * mean;
    float inv  = rsqrtf(var + 1e-5f);
    out[(size_t)r * 128 + c] = (x - mean) * inv * g[c] + beta[c];
}

// ---------------------------------------------------------------------------
// V transpose: out[z][d][n] = in[z1*inz1 + z2*inz2 + n*ldin + d], d<128.
// ---------------------------------------------------------------------------
__global__ __launch_bounds__(256)
void transp128(const ushort_t* __restrict__ in, ushort_t* __restrict__ out,
               int ldin, long inz1, long inz2, long outz)
{
    __shared__ ushort_t T[64][136];
    const int z = blockIdx.z, z1 = z & 7, z2 = z >> 3;
    const int n0 = blockIdx.x * 64;
    const ushort_t* ip = in + (size_t)z1 * inz1 + (size_t)z2 * inz2;
    const int rr = threadIdx.x >> 2, cg = (threadIdx.x & 3) * 32;
#pragma unroll
    for (int c = 0; c < 4; c++) {
        s16x8 v = *(const s16x8*)(ip + (size_t)(n0 + rr) * ldin + cg + c * 8);
        *(s16x8*)&T[rr][cg + c * 8] = v;
    }
    __syncthreads();
    const int d = threadIdx.x >> 1, j0 = (threadIdx.x & 1) * 32;
    ushort_t* op = out + (size_t)z * outz + (size_t)d * 1024 + n0 + j0;
#pragma unroll
    for (int c = 0; c < 4; c++) {
        s16x8 v;
#pragma unroll
        for (int j = 0; j < 8; j++) v[j] = (short)T[j0 + c * 8 + j][d];
        *(s16x8*)(op + c * 8) = v;
    }
}

// ---------------------------------------------------------------------------
// Collapsed feature-attention precompute
// consts (floats): u@0(384) v@512(384) abcd@1024(16) wv@1088(512) c0@1600(128)
// Gb packed: bf16[2048][8]: cols 0..3 = g[m][h], col 4 = g0[m], 5..7 = 0
// ---------------------------------------------------------------------------
__global__ void precomp1(const float* __restrict__ fa_wi, const float* __restrict__ fa_bi,
                         const float* __restrict__ pl1_w, const float* __restrict__ pl1_b,
                         float* __restrict__ consts)
{
    int j = threadIdx.x;
    if (j < 384) {
        float u = 0.f, v = 0.f;
        for (int k = 0; k < 128; k++) {
            float w = fa_wi[j * 128 + k];
            u = fmaf(w, pl1_w[k], u);
            v = fmaf(w, pl1_b[k], v);
        }
        consts[j]       = u;
        consts[512 + j] = v + fa_bi[j];
    }
}

__global__ void precomp2(const float* __restrict__ fa_wo, const float* __restrict__ fa_bo,
                         float* __restrict__ consts)
{
    int tid = threadIdx.x;  // 128
    const float* u = consts;
    const float* v = consts + 512;
    if (tid < 16) {
        int h = tid >> 2, w = tid & 3;
        const float* ql = (w < 2) ? u : v;
        const float* kr = ((w & 1) == 0) ? u : v;
        float acc = 0.f;
        for (int d = 0; d < 32; d++) acc += ql[h * 32 + d] * kr[128 + h * 32 + d];
        consts[1024 + tid] = acc * 0.17677669529663687f;
    }
#pragma unroll
    for (int h = 0; h < 4; h++) {
        float acc = 0.f;
        for (int d = 0; d < 32; d++)
            acc = fmaf(fa_wo[tid * 128 + h * 32 + d], u[256 + h * 32 + d], acc);
        consts[1088 + h * 128 + tid] = acc;
    }
    float c0 = fa_bo[tid];
    for (int idx = 0; idx < 128; idx++)
        c0 = fmaf(fa_wo[tid * 128 + idx], v[256 + idx], c0);
    consts[1600 + tid] = c0;
}

__global__ void precomp3(const float* __restrict__ pl2_w, const float* __restrict__ pl2_b,
                         const float* __restrict__ consts, ushort_t* __restrict__ Gb)
{
    int m = blockIdx.x * 256 + threadIdx.x;   // 2048
    const float* wv = consts + 1088;
    const float* c0 = consts + 1600;
    float a0 = 0.f, ah[4] = {0.f, 0.f, 0.f, 0.f};
    for (int j = 0; j < 128; j++) {
        float w = pl2_w[m * 128 + j];
        ah[0] = fmaf(w, wv[0 * 128 + j], ah[0]);
        ah[1] = fmaf(w, wv[1 * 128 + j], ah[1]);
        ah[2] = fmaf(w, wv[2 * 128 + j], ah[2]);
        ah[3] = fmaf(w, wv[3 * 128 + j], ah[3]);
        a0    = fmaf(w, c0[j], a0);
    }
    ushort_t row[8];
#pragma unroll
    for (int h = 0; h < 4; h++) row[h] = f2bf(ah[h]);
    row[4] = f2bf(a0 + pl2_b[m]);
    row[5] = row[6] = row[7] = 0;
    *(uint4*)&Gb[m * 8] = *(uint4*)row;
}

// ---------------------------------------------------------------------------
// feat_t: per-token feature attention (moment softmax) -> packed T table
// Tp[(n*128+f)*8] = [t0 t1 t2 t3 1 0 0 0] bf16. 2304 blocks x 128 thr.
// ---------------------------------------------------------------------------
__global__ __launch_bounds__(128)
void feat_t(const float* __restrict__ src, const float* __restrict__ consts,
            ushort_t* __restrict__ Tp)
{
    __shared__ float sv[128];
    __shared__ float red[2];
    const int n = blockIdx.x, f = threadIdx.x;
    const float si = src[n * 128 + f];
    sv[f] = si;
    __syncthreads();

    float S1 = block_reduce(si, 0, red);
    float S2 = block_reduce(si * si, 0, red);
    float S3 = block_reduce(si * si * si, 0, red);
    float S4 = block_reduce(si * si * si * si, 0, red);
    float amax = block_reduce(fabsf(si), 1, red);

    float ph[4];
#pragma unroll
    for (int h = 0; h < 4; h++)
        ph[h] = consts[1024 + h * 4 + 0] * si + consts[1024 + h * 4 + 2];
    float pm = fmaxf(fmaxf(fabsf(ph[0]), fabsf(ph[1])), fmaxf(fabsf(ph[2]), fabsf(ph[3])));
    float pmax = block_reduce(pm, 1, red);

    ushort_t row[8];
    if (pmax * amax < 0.25f) {   // Taylor regime (block-uniform)
#pragma unroll
        for (int h = 0; h < 4; h++) {
            float p = ph[h];
            float num = fmaf(p, fmaf(p, fmaf(p, S4 * (1.f / 6.f), 0.5f * S3), S2), S1);
            float den = fmaf(p, fmaf(p, fmaf(p, S3 * (1.f / 6.f), 0.5f * S2), S1), 128.f);
            row[h] = f2bf(num / den);
        }
    } else {                     // exact fallback
        float smax = block_reduce(si, 1, red);
        float smin = -block_reduce(-si, 1, red);
#pragma unroll
        for (int h = 0; h < 4; h++) {
            float p = ph[h];
            float m = fmaxf(p * smax, p * smin);
            float l = 0.f, t = 0.f;
            for (int j = 0; j < 128; j++) {
                float e = __expf(fmaf(p, sv[j], -m));
                l += e; t = fmaf(e, sv[j], t);
            }
            row[h] = f2bf(t / l);
        }
    }
    row[4] = 0x3F80;   // 1.0 (carries g0)
    row[5] = row[6] = row[7] = 0;
    *(uint4*)&Tp[(size_t)(n * 128 + f) * 8] = *(uint4*)row;
}

// ---------------------------------------------------------------------------
// mlp_ln v2: y = relu(T@G^T)·w + residual -> LN.  NO LDS staging, no barriers
// in the m-loop: G and pl3_w are streamed from global (L2-hot, 40 KB shared by
// all 2304 blocks). Occupancy is VGPR-bound only.
// 512 threads (8 waves): wave = (mq, fhalf); 32 m-iterations each.
// ---------------------------------------------------------------------------
__global__ __launch_bounds__(512)
void mlp_ln(const ushort_t* __restrict__ Tp, const float* __restrict__ src,
            const ushort_t* __restrict__ Gb, const float* __restrict__ pl3_w,
            const float* __restrict__ pl3_b, const float* __restrict__ pn1_g,
            const float* __restrict__ pn1_b, ushort_t* __restrict__ src1)
{
    __shared__ float ypart[512];
    __shared__ float red[8];

    const int n   = blockIdx.x;
    const int tid = threadIdx.x;        // 0..511

    const int wave = tid >> 6, lane = tid & 63;
    const int wm = (wave & 1) * 64;     // f half
    const int mq = wave >> 1;           // m quarter (0..3)
    const int mi = lane & 15, quad = lane >> 4;

    // A fragments straight from global T (L2-hot); quads 1..3 exact zero.
    s16x8 af[4];
#pragma unroll
    for (int t = 0; t < 4; t++) {
        s16x8 v = *(const s16x8*)&Tp[((size_t)n * 128 + wm + t * 16 + mi) * 8];
        af[t] = (quad == 0) ? v : (s16x8)0;
    }

    f32x2 partial2[4][2];
#pragma unroll
    for (int i = 0; i < 4; i++) { partial2[i][0] = (f32x2)0.f; partial2[i][1] = (f32x2)0.f; }
    const f32x2 zero2 = (f32x2)0.f;

#pragma unroll 4
    for (int mt = 0; mt < 32; mt++) {
        const int m0 = mq * 512 + mt * 16;
        s16x8 bfr = *(const s16x8*)&Gb[(size_t)(m0 + mi) * 8];   // global, L2-hot
        float w = pl3_w[m0 + mi];                                // global, L2-hot
        f32x2 w2 = { w, w };
        f32x4 acc[4];
#pragma unroll
        for (int tm = 0; tm < 4; tm++)
            acc[tm] = __builtin_amdgcn_mfma_f32_16x16x32_bf16(af[tm], bfr, (f32x4)0.f, 0, 0, 0);
#pragma unroll
        for (int tm = 0; tm < 4; tm++) {
            f32x2* pa = (f32x2*)&acc[tm];
#pragma unroll
            for (int i = 0; i < 2; i++) {
                f32x2 r = __builtin_elementwise_max(pa[i], zero2);   // v_pk_max_f32
                partial2[tm][i] = r * w2 + partial2[tm][i];          // v_pk_fma_f32
            }
        }
    }

    // reduce across the 16 mi lanes (same f rows)
#pragma unroll
    for (int tm = 0; tm < 4; tm++)
#pragma unroll
        for (int r = 0; r < 4; r++) {
            float v = partial2[tm][r >> 1][r & 1];
            v += __shfl_xor(v, 8);
            v += __shfl_xor(v, 4);
            v += __shfl_xor(v, 2);
            v += __shfl_xor(v, 1);
            if (mi == 0) ypart[mq * 128 + wm + tm * 16 + quad * 4 + r] = v;
        }
    __syncthreads();

    float yv = 0.f;
    const int f = tid & 127;
    if (tid < 128)
        yv = ypart[f] + ypart[128 + f] + ypart[256 + f] + ypart[384 + f]
           + pl3_b[0] + src[n * 128 + f];
    float s  = block_reduce(yv, 0, red);
    float ss = block_reduce(yv * yv, 0, red);
    float mean = s * (1.f / 128.f);
    float var  = ss * (1.f / 128.f) - mean * mean;
    float inv  = rsqrtf(var + 1e-5f);
    if (tid < 128)
        src1[n * 128 + f] = f2bf((yv - mean) * inv * pn1_g[f] + pn1_b[f]);
}

// LN over bf16: out = LN(a [+ b]) * g + beta;  out bf16 or fp32
template<bool OUTF32>
__global__ void ln_bf16(const ushort_t* __restrict__ a, const ushort_t* __restrict__ b,
                        const ushort_t* __restrict__ post, const float* __restrict__ g,
                        const float* __restrict__ beta, void* __restrict__ out, int D)
{
    __shared__ float red[4];
    const size_t row = blockIdx.x;
    const int tid = threadIdx.x;
    const int nit = D / blockDim.x;   // <= 4
    const ushort_t* ap = a + row * D;
    const ushort_t* bp = b ? b + row * D : nullptr;
    float xr[4];
    float s = 0.f, ss = 0.f;
    for (int i = 0; i < nit; i++) {
        int idx = i * blockDim.x + tid;
        float x = bf2f(ap[idx]) + (bp ? bf2f(bp[idx]) : 0.f);
        xr[i] = x; s += x; ss = fmaf(x, x, ss);
    }
    s  = block_reduce(s, 0, red);
    ss = block_reduce(ss, 0, red);
    float mean = s / D, var = ss / D - mean * mean;
    float inv = rsqrtf(var + 1e-5f);
    const ushort_t* pp = post ? post + row * D : nullptr;
    for (int i = 0; i < nit; i++) {
        int idx = i * blockDim.x + tid;
        float v = (xr[i] - mean) * inv * g[idx] + beta[idx];
        if (pp) v += bf2f(pp[idx]);
        if (OUTF32) ((float*)out)[row * D + idx] = v;
        else        ((ushort_t*)out)[row * D + idx] = f2bf(v);
    }
}

// LN over concat(a1[0:split], Σparts+bias2 [rows>=split]) + b -> bf16, D=1024
__global__ __launch_bounds__(256)
void ln_cat2(const ushort_t* __restrict__ a1, const float* __restrict__ parts,
             long pstride, int P, const float* __restrict__ bias2, int split,
             const ushort_t* __restrict__ b, const float* __restrict__ g,
             const float* __restrict__ beta, ushort_t* __restrict__ out)
{
    __shared__ float red[4];
    const int row = blockIdx.x;
    const int tid = threadIdx.x;
    float xr[4];
    float s = 0.f, ss = 0.f;
#pragma unroll
    for (int i = 0; i < 4; i++) {
        int idx = i * 256 + tid;
        float x;
        if (row < split) {
            x = bf2f(a1[(size_t)row * 1024 + idx]);
        } else {
            int r2 = row - split;
            x = bias2[idx];
            for (int p = 0; p < P; p++)
                x += parts[(size_t)p * pstride + (size_t)r2 * 1024 + idx];
        }
        x += bf2f(b[(size_t)row * 1024 + idx]);
        xr[i] = x; s += x; ss = fmaf(x, x, ss);
    }
    s  = block_reduce(s, 0, red);
    ss = block_reduce(ss, 0, red);
    float mean = s * (1.f / 1024.f);
    float var  = ss * (1.f / 1024.f) - mean * mean;
    float inv  = rsqrtf(var + 1e-5f);
#pragma unroll
    for (int i = 0; i < 4; i++) {
        int idx = i * 256 + tid;
        out[(size_t)row * 1024 + idx] = f2bf((xr[i] - mean) * inv * g[idx] + beta[idx]);
    }
}

// row softmax in place, bf16, cols == 1024, 256 threads
__global__ __launch_bounds__(256)
void softmax_bf16(ushort_t* __restrict__ S)
{
    __shared__ float red[4];
    const size_t row = blockIdx.x;
    ushort_t* p = S + row * 1024;
    const int tid = threadIdx.x;
    uint2 u = *(const uint2*)&p[tid * 4];
    ushort_t* us = (ushort_t*)&u;
    float xr[4];
    float mx = -3.4e38f;
#pragma unroll
    for (int i = 0; i < 4; i++) { xr[i] = bf2f(us[i]); mx = fmaxf(mx, xr[i]); }
    mx = block_reduce(mx, 1, red);
    float sum = 0.f;
#pragma unroll
    for (int i = 0; i < 4; i++) { xr[i] = __expf(xr[i] - mx); sum += xr[i]; }
    sum = block_reduce(sum, 0, red);
    float inv = 1.f / sum;
#pragma unroll
    for (int i = 0; i < 4; i++) us[i] = f2bf(xr[i] * inv);
    *(uint2*)&p[tid * 4] = u;
}

// ---------------------------------------------------------------------------
// Host side
// ---------------------------------------------------------------------------
static inline void gemm_go(hipStream_t s, const ushort_t* A, const ushort_t* B,
                           const float* bias, ushort_t* C,
                           int M, int N, int K, int lda, int ldb, int ldc,
                           long sAz, long sBz, long sCz, int Z, float alpha,
                           bool relu,
                           long sA2 = 0, long sB2 = 0, long sC2 = 0, int zshift = 0,
                           int ksplit = 1, float* Cp = nullptr, long pstride = 0)
{
    dim3 g(M / 128, N / 128, Z * ksplit), b(256);
    int ksplen = K / ksplit;
    if (ksplit > 1)
        gemm_bf16<false, true ><<<g, b, 0, s>>>(A, B, nullptr, nullptr, Cp, pstride, ksplen, Z,
            M, N, K, lda, ldb, ldc, sAz, sBz, sCz, sA2, sB2, sC2, zshift, alpha);
    else if (relu)
        gemm_bf16<true,  false><<<g, b, 0, s>>>(A, B, bias, C, nullptr, 0, 0, Z,
            M, N, K, lda, ldb, ldc, sAz, sBz, sCz, sA2, sB2, sC2, zshift, alpha);
    else
        gemm_bf16<false, false><<<g, b, 0, s>>>(A, B, bias, C, nullptr, 0, 0, Z,
            M, N, K, lda, ldb, ldc, sAz, sBz, sCz, sA2, sB2, sC2, zshift, alpha);
}

extern "C" void kernel_launch(void* const* d_in, const int* in_sizes, int n_in,
                              void* d_out, int out_size, void* d_ws, size_t ws_size,
                              hipStream_t stream)
{
    const float* src   = (const float*)d_in[0];
    const float* sa_wi = (const float*)d_in[2];
    const float* sa_bi = (const float*)d_in[3];
    const float* sa_wo = (const float*)d_in[4];
    const float* sa_bo = (const float*)d_in[5];
    const float* fa_wi = (const float*)d_in[6];
    const float* fa_bi = (const float*)d_in[7];
    const float* fa_wo = (const float*)d_in[8];
    const float* fa_bo = (const float*)d_in[9];
    const float* pl1_w = (const float*)d_in[10];
    const float* pl1_b = (const float*)d_in[11];
    const float* pl2_w = (const float*)d_in[12];
    const float* pl2_b = (const float*)d_in[13];
    const float* pl3_w = (const float*)d_in[14];
    const float* pl3_b = (const float*)d_in[15];
    const float* pl4_w = (const float*)d_in[16];
    const float* pl4_b = (const float*)d_in[17];
    const float* pl5_w = (const float*)d_in[18];
    const float* pl5_b = (const float*)d_in[19];
    const float* pl6_w = (const float*)d_in[20];
    const float* pl6_b = (const float*)d_in[21];
    const float* pl7_w = (const float*)d_in[22];
    const float* pl7_b = (const float*)d_in[23];
    const float* l1_w  = (const float*)d_in[24];
    const float* l1_b  = (const float*)d_in[25];
    const float* l2_w  = (const float*)d_in[26];
    const float* l2_b  = (const float*)d_in[27];
    const float* pn1_g = (const float*)d_in[28];
    const float* pn1_b = (const float*)d_in[29];
    const float* pn2_g = (const float*)d_in[30];
    const float* pn2_b = (const float*)d_in[31];
    const float* n1_g  = (const float*)d_in[32];
    const float* n1_b  = (const float*)d_in[33];
    const float* n2_g  = (const float*)d_in[34];
    const float* n2_b  = (const float*)d_in[35];

    float* ws  = (float*)d_ws;
    float* out = (float*)d_out;

    float* CONSTS = ws;                   // 16384 floats
    ushort_t* wsb = (ushort_t*)(ws + 16384);
    ushort_t* SAWIb  = wsb + 0;           // 3145728
    ushort_t* SAWOb  = wsb + 3145728;     // 1048576
    ushort_t* PL4b   = wsb + 4194304;     // 262144
    ushort_t* PL5b   = wsb + 4456448;     // 2097152
    ushort_t* PL6b   = wsb + 6553600;     // 2097152
    ushort_t* PL7b   = wsb + 8650752;     // 2097152
    ushort_t* L1b    = wsb + 10747904;    // 2097152
    ushort_t* L2b    = wsb + 12845056;    // 262144
    ushort_t* Gbb    = wsb + 13107200;    // 65536 (packed 2048x8 used)
    ushort_t* SRC1b  = wsb + 13172736;    // 294912
    ushort_t* HBIGb  = wsb + 13467648;    // 4718592 (2304x2048; also VT scratch)
    ushort_t* SRC1_b = wsb + 18186240;    // 2359296 (2304x1024)
    ushort_t* QKVb   = wsb + 20545536;    // 7077888 (2304x3072)
    ushort_t* SBUFb  = wsb + 27623424;    // 16777216 (scores / cross / splitK partials)
    ushort_t* OBUFb  = wsb + 44400640;    // 2097152 (contiguous after SBUF)
    ushort_t* SLb    = wsb + 46497792;    // 2097152
    ushort_t* SLPb   = wsb + 48594944;    // 2097152
    ushort_t* SOb    = wsb + 50692096;    // 2359296
    ushort_t* TPb    = wsb + 53051392;    // 2359296 (packed T table)
    // total ~111 MB
    float* PARTS = (float*)SBUFb;         // fp32 split-K partials (time-shared)

    // ---- one-time weight conversion (single dispatch) ----
    {
        CvtArgs a;
        const float* srcs[8] = { sa_wi, sa_wo, pl4_w, pl5_w, pl6_w, pl7_w, l1_w, l2_w };
        ushort_t*    dsts[8] = { SAWIb, SAWOb, PL4b, PL5b, PL6b, PL7b, L1b, L2b };
        int          ns[8]   = { 3145728, 1048576, 262144, 2097152, 2097152, 2097152, 2097152, 262144 };
        int cum = 0;
        for (int i = 0; i < 8; i++) { a.src[i] = srcs[i]; a.dst[i] = dsts[i]; cum += ns[i] / 4; a.end[i] = cum; }
        cvt_all<<<(cum + 255) / 256, 256, 0, stream>>>(a);
    }

    // ---- collapsed feature-attention block ----
    precomp1<<<1, 384, 0, stream>>>(fa_wi, fa_bi, pl1_w, pl1_b, CONSTS);
    precomp2<<<1, 128, 0, stream>>>(fa_wo, fa_bo, CONSTS);
    precomp3<<<8, 256, 0, stream>>>(pl2_w, pl2_b, CONSTS, Gbb);
    feat_t<<<2304, 128, 0, stream>>>(src, CONSTS, TPb);
    mlp_ln<<<2304, 512, 0, stream>>>(TPb, src, Gbb, pl3_w, pl3_b, pn1_g, pn1_b, SRC1b);

    // ---- src1_ = relu(src1@pl4^T+b)@pl5^T+b  (pl5 split-K x2) ----
    gemm_go(stream, SRC1b, PL4b, pl4_b, HBIGb, 2304, 2048, 128, 128, 128, 2048, 0, 0, 0, 1, 1.f, true);
    gemm_go(stream, HBIGb, PL5b, nullptr, nullptr, 2304, 1024, 2048, 2048, 2048, 1024, 0, 0, 0, 1, 1.f, false,
            0, 0, 0, 0, 2, PARTS, 2359296);
    sum_cvt<false><<<2304, 256, 0, stream>>>(PARTS, 2359296, 2, pl5_b, 1024, SRC1_b, 589824);

    // ---- qkv over ALL 2304 rows (rows 2048+ give cross-attn Q for free) ----
    gemm_go(stream, SRC1_b, SAWIb, sa_bi, QKVb, 2304, 3072, 1024, 1024, 1024, 3072, 0, 0, 0, 1, 1.f, false);
    const float iscale = 0.08838834764831845f;   // 1/sqrt(128)
    ushort_t* VT1 = HBIGb;
    transp128<<<dim3(16, 1, 16), 256, 0, stream>>>(QKVb + 2048, VT1, 6144, 128, 3072, 131072);
    // self-attention on rows 0..2047, z = h + 8*b
    gemm_go(stream, QKVb, QKVb + 1024, nullptr, SBUFb,
            1024, 1024, 128, 6144, 6144, 1024, 128, 128, 1048576, 16, iscale, false,
            3072, 3072, 8388608, 3);
    softmax_bf16<<<16384, 256, 0, stream>>>(SBUFb);
    gemm_go(stream, SBUFb, VT1, nullptr, OBUFb,
            1024, 128, 1024, 1024, 1024, 2048, 1048576, 131072, 128, 16, 1.f, false,
            8388608, 1048576, 1024, 3);
    // wo split-K x2 + fused reduce+LN (scores dead, PARTS = SBUF)
    gemm_go(stream, OBUFb, SAWOb, nullptr, nullptr, 2048, 1024, 1024, 1024, 1024, 1024, 0, 0, 0, 1, 1.f, false,
            0, 0, 0, 0, 2, PARTS, 2097152);
    sum_ln<<<2048, 256, 0, stream>>>(PARTS, 2097152, 2, sa_bo, SRC1_b, nullptr, pn2_g, pn2_b, SLb);

    // ---- sl_ = ln(relu(sl@pl6^T)@pl7^T, pn2) + sl ----
    gemm_go(stream, SLb, PL6b, nullptr, nullptr, 2048, 2048, 1024, 1024, 1024, 2048, 0, 0, 0, 1, 1.f, false,
            0, 0, 0, 0, 2, PARTS, 4194304);
    sum_cvt<true><<<4096, 256, 0, stream>>>(PARTS, 4194304, 2, pl6_b, 2048, HBIGb, 1048576);
    gemm_go(stream, HBIGb, PL7b, nullptr, nullptr, 2048, 1024, 2048, 2048, 2048, 1024, 0, 0, 0, 1, 1.f, false,
            0, 0, 0, 0, 2, PARTS, 2097152);
    sum_ln<<<2048, 256, 0, stream>>>(PARTS, 2097152, 2, pl7_b, nullptr, SLb, pn2_g, pn2_b, SLPb);

    // ---- cross-attention: q from qkv rows 2048+, k/v from sl_ ----
    ushort_t* KV2 = SBUFb;               // 2048x2048
    ushort_t* S2  = SBUFb + 4456448;     // 16x128x1024
    gemm_go(stream, SLPb, SAWIb + 1024 * 1024, sa_bi + 1024, KV2, 2048, 2048, 1024, 1024, 1024, 2048, 0, 0, 0, 1, 1.f, false);
    ushort_t* VT2 = HBIGb;
    transp128<<<dim3(16, 1, 16), 256, 0, stream>>>(KV2 + 1024, VT2, 4096, 128, 2048, 131072);
    gemm_go(stream, QKVb + 2048 * 3072, KV2, nullptr, S2,
            128, 1024, 128, 6144, 4096, 1024, 128, 128, 131072, 16, iscale, false,
            3072, 2048, 1048576, 3);
    softmax_bf16<<<2048, 256, 0, stream>>>(S2);
    gemm_go(stream, S2, VT2, nullptr, nullptr,
            128, 128, 1024, 1024, 1024, 2048, 131072, 131072, 128, 16, 1.f, false,
            1048576, 1048576, 1024, 3, 8, PARTS, 262144);
    sum_cvt<false><<<256, 256, 0, stream>>>(PARTS, 262144, 8, nullptr, 2048, OBUFb, 65536);
    // sr-out split-K x8; reduce folded into ln_cat2
    gemm_go(stream, OBUFb, SAWOb, nullptr, nullptr, 256, 1024, 1024, 1024, 1024, 1024, 0, 0, 0, 1, 1.f, false,
            0, 0, 0, 0, 8, PARTS, 262144);

    // ---- so = ln(concat(sl, sr) + src1_, n1)  (sr reduce fused) ----
    ln_cat2<<<2304, 256, 0, stream>>>(SLb, PARTS, 262144, 8, sa_bo, 2048, SRC1_b, n1_g, n1_b, SOb);

    // ---- ff = relu(so@l1^T)@l2^T ; out = ln(src1 + ff, n2) ----
    gemm_go(stream, SOb, L1b, nullptr, nullptr, 2304, 2048, 1024, 1024, 1024, 2048, 0, 0, 0, 1, 1.f, false,
            0, 0, 0, 0, 2, PARTS, 4718592);
    sum_cvt<true><<<4608, 256, 0, stream>>>(PARTS, 4718592, 2, l1_b, 2048, HBIGb, 1179648);
    gemm_go(stream, HBIGb, L2b, nullptr, nullptr, 2304, 128, 2048, 2048, 2048, 128, 0, 0, 0, 1, 1.f, false,
            0, 0, 0, 0, 8, PARTS, 294912);
    ln_part<<<2304, 128, 0, stream>>>(PARTS, 294912, 8, l2_b, SRC1b, n2_g, n2_b, out);
}

// Round 11
// 550.353 us; speedup vs baseline: 1.0769x; 1.0769x over previous
//
#include <hip/hip_runtime.h>

using s16x8  = __attribute__((ext_vector_type(8))) short;   // 8 bf16 (4 VGPRs)
using f32x4  = __attribute__((ext_vector_type(4))) float;   // MFMA acc 16x16
using f32x16 = __attribute__((ext_vector_type(16))) float;  // MFMA acc 32x32
using f32x2  = __attribute__((ext_vector_type(2))) float;   // packed fp32
typedef unsigned short ushort_t;

__device__ __forceinline__ unsigned short f2bf(float f) {
    union { float f; unsigned u; } v; v.f = f;
    unsigned u = v.u + 0x7FFFu + ((v.u >> 16) & 1u);   // round-nearest-even
    return (unsigned short)(u >> 16);
}
__device__ __forceinline__ float bf2f(unsigned short h) {
    union { unsigned u; float f; } v; v.u = ((unsigned)h) << 16;
    return v.f;
}

// block reduction: op==0 sum, op==1 max. lds >= blockDim/64 floats.
__device__ __forceinline__ float block_reduce(float v, int op, float* lds) {
    const int lane = threadIdx.x & 63;
    const int w    = threadIdx.x >> 6;
    const int nw   = blockDim.x >> 6;
#pragma unroll
    for (int off = 32; off > 0; off >>= 1) {
        float o = __shfl_down(v, off, 64);
        v = op ? fmaxf(v, o) : (v + o);
    }
    __syncthreads();
    if (lane == 0) lds[w] = v;
    __syncthreads();
    float r = lds[0];
    for (int i = 1; i < nw; i++) r = op ? fmaxf(r, lds[i]) : (r + lds[i]);
    return r;
}

__device__ __forceinline__ void load_lds16(const void* g, void* l) {
    __builtin_amdgcn_global_load_lds(
        (const __attribute__((address_space(1))) unsigned int*)g,
        (__attribute__((address_space(3))) unsigned int*)l, 16, 0, 0);
}

// ---------------------------------------------------------------------------
// fp32 -> bf16 weight conversion, all 8 weights in one dispatch
// ---------------------------------------------------------------------------
struct CvtArgs { const float* src[8]; ushort_t* dst[8]; int end[8]; };

__global__ __launch_bounds__(256)
void cvt_all(CvtArgs a)
{
    int i = blockIdx.x * 256 + threadIdx.x;
    int j = 0;
    while (j < 8 && i >= a.end[j]) j++;
    if (j >= 8) return;
    int li = i - (j ? a.end[j - 1] : 0);
    float4 v = *(const float4*)&a.src[j][(size_t)li * 4];
    ushort_t u[4] = { f2bf(v.x), f2bf(v.y), f2bf(v.z), f2bf(v.w) };
    *(uint2*)&a.dst[j][(size_t)li * 4] = *(uint2*)u;
}

// ---------------------------------------------------------------------------
// bf16 GEMM, BK=64, XOR-swizzled LDS (slot g' holds global group g'^(r&7)).
//   Normal:  C[z] = act(alpha*A[z]@B[z]^T + bias), bf16 out.
//   SPLITK:  blockIdx.z = ks*zmod + zb; K-chunk [ks*ksplen,+ksplen), raw fp32
//            (alpha applied, no bias/act) to Cp + ks*pstride + usual index.
// M%128==0, N%128==0, K%64==0 (ksplen%64==0).
// ---------------------------------------------------------------------------
template<bool RELU, bool SPLITK>
__global__ __launch_bounds__(256, 2)
void gemm_bf16(const ushort_t* __restrict__ A, const ushort_t* __restrict__ B,
               const float* __restrict__ bias, ushort_t* __restrict__ C,
               float* __restrict__ Cp, long pstride, int ksplen, int zmod,
               int M, int N, int K, int lda, int ldb, int ldc,
               long sAz, long sBz, long sCz, long sA2, long sB2, long sC2,
               int zshift, float alpha)
{
    __shared__ ushort_t As[128 * 64];
    __shared__ ushort_t Bs[128 * 64];

    const int tid = threadIdx.x;
    int zz = blockIdx.z;
    int ks = 0, z = zz;
    if (SPLITK) { ks = zz / zmod; z = zz - ks * zmod; }
    const int z1  = z & ((1 << zshift) - 1);
    const int z2  = z >> zshift;
    const int m0  = blockIdx.x * 128;
    const int n0  = blockIdx.y * 128;

    const ushort_t* Ab = A + (size_t)z1 * sAz + (size_t)z2 * sA2 + (size_t)m0 * lda;
    const ushort_t* Bb = B + (size_t)z1 * sBz + (size_t)z2 * sB2 + (size_t)n0 * ldb;

    const int wave = tid >> 6, lane = tid & 63;
    const int wm = (wave & 1) * 64, wn = (wave >> 1) * 64;
    const int mi = lane & 15, quad = lane >> 4;

    f32x4 acc[4][4];
#pragma unroll
    for (int i = 0; i < 4; i++)
#pragma unroll
        for (int j = 0; j < 4; j++) acc[i][j] = (f32x4)0.f;

    // staging: chunk ci = tid + p*256 -> LDS slot (r=ci>>3, g'=ci&7);
    // fetch global group g = g' ^ (r&7)
    int rs[4], gs[4];
#pragma unroll
    for (int p = 0; p < 4; p++) {
        int ci = tid + p * 256;
        rs[p] = ci >> 3;
        gs[p] = (ci & 7) ^ (rs[p] & 7);
    }

    const int kbeg = SPLITK ? ks * ksplen : 0;
    const int kend = SPLITK ? kbeg + ksplen : K;

    for (int k0 = kbeg; k0 < kend; k0 += 64) {
#pragma unroll
        for (int p = 0; p < 4; p++)
            load_lds16(Ab + (size_t)rs[p] * lda + k0 + gs[p] * 8, &As[(tid + p * 256) * 8]);
#pragma unroll
        for (int p = 0; p < 4; p++)
            load_lds16(Bb + (size_t)rs[p] * ldb + k0 + gs[p] * 8, &Bs[(tid + p * 256) * 8]);
        __syncthreads();

#pragma unroll
        for (int sub = 0; sub < 2; sub++) {
            s16x8 af[4], bfr[4];
#pragma unroll
            for (int t = 0; t < 4; t++) {
                int r = wm + t * 16 + mi;
                af[t] = *(const s16x8*)&As[r * 64 + (((sub * 4 + quad) ^ (r & 7)) * 8)];
            }
#pragma unroll
            for (int t = 0; t < 4; t++) {
                int r = wn + t * 16 + mi;
                bfr[t] = *(const s16x8*)&Bs[r * 64 + (((sub * 4 + quad) ^ (r & 7)) * 8)];
            }
#pragma unroll
            for (int tm = 0; tm < 4; tm++)
#pragma unroll
                for (int tn = 0; tn < 4; tn++)
                    acc[tm][tn] = __builtin_amdgcn_mfma_f32_16x16x32_bf16(af[tm], bfr[tn], acc[tm][tn], 0, 0, 0);
        }
        __syncthreads();
    }

    if (SPLITK) {
        float* Cf = Cp + (size_t)ks * pstride + (size_t)z1 * sCz + (size_t)z2 * sC2;
#pragma unroll
        for (int tn = 0; tn < 4; tn++) {
            int col = n0 + wn + tn * 16 + mi;
#pragma unroll
            for (int tm = 0; tm < 4; tm++)
#pragma unroll
                for (int r = 0; r < 4; r++) {
                    int row = m0 + wm + tm * 16 + quad * 4 + r;
                    Cf[(size_t)row * ldc + col] = acc[tm][tn][r] * alpha;
                }
        }
    } else {
#pragma unroll
        for (int tn = 0; tn < 4; tn++) {
            int col = n0 + wn + tn * 16 + mi;
            float bv = bias ? bias[col] : 0.f;
#pragma unroll
            for (int tm = 0; tm < 4; tm++) {
#pragma unroll
                for (int r = 0; r < 4; r++) {
                    int row = m0 + wm + tm * 16 + quad * 4 + r;
                    float v = acc[tm][tn][r] * alpha + bv;
                    if (RELU) v = fmaxf(v, 0.f);
                    C[(size_t)z1 * sCz + (size_t)z2 * sC2 + (size_t)row * ldc + col] = f2bf(v);
                }
            }
        }
    }
}

// sum P fp32 partials (+bias per col) [relu] -> bf16
template<bool RELU>
__global__ __launch_bounds__(256)
void sum_cvt(const float* __restrict__ parts, long pstride, int P,
             const float* __restrict__ bias, int ldc,
             ushort_t* __restrict__ out, int total4)
{
    int i = blockIdx.x * 256 + threadIdx.x;
    if (i >= total4) return;
    size_t idx = (size_t)i * 4;
    float4 s = *(const float4*)&parts[idx];
    for (int p = 1; p < P; p++) {
        float4 v = *(const float4*)&parts[(size_t)p * pstride + idx];
        s.x += v.x; s.y += v.y; s.z += v.z; s.w += v.w;
    }
    if (bias) {
        int col = (int)(idx % (size_t)ldc);
        s.x += bias[col]; s.y += bias[col + 1]; s.z += bias[col + 2]; s.w += bias[col + 3];
    }
    if (RELU) {
        s.x = fmaxf(s.x, 0.f); s.y = fmaxf(s.y, 0.f);
        s.z = fmaxf(s.z, 0.f); s.w = fmaxf(s.w, 0.f);
    }
    ushort_t u[4] = { f2bf(s.x), f2bf(s.y), f2bf(s.z), f2bf(s.w) };
    *(uint2*)&out[idx] = *(uint2*)u;
}

// fused split-K reduce + LN:  out = LN(Σ parts + bias [+ residB]) * g + beta [+ post]
__global__ __launch_bounds__(256)
void sum_ln(const float* __restrict__ parts, long pstride, int P,
            const float* __restrict__ bias, const ushort_t* __restrict__ residB,
            const ushort_t* __restrict__ post, const float* __restrict__ g,
            const float* __restrict__ beta, ushort_t* __restrict__ out)
{
    __shared__ float red[4];
    const size_t row = blockIdx.x;
    const int tid = threadIdx.x;
    float xr[4];
    float s = 0.f, ss = 0.f;
#pragma unroll
    for (int i = 0; i < 4; i++) {
        int idx = i * 256 + tid;
        float x = bias[idx];
        for (int p = 0; p < P; p++) x += parts[(size_t)p * pstride + row * 1024 + idx];
        if (residB) x += bf2f(residB[row * 1024 + idx]);
        xr[i] = x; s += x; ss = fmaf(x, x, ss);
    }
    s  = block_reduce(s, 0, red);
    ss = block_reduce(ss, 0, red);
    float mean = s * (1.f / 1024.f);
    float var  = ss * (1.f / 1024.f) - mean * mean;
    float inv  = rsqrtf(var + 1e-5f);
#pragma unroll
    for (int i = 0; i < 4; i++) {
        int idx = i * 256 + tid;
        float v = (xr[i] - mean) * inv * g[idx] + beta[idx];
        if (post) v += bf2f(post[row * 1024 + idx]);
        out[row * 1024 + idx] = f2bf(v);
    }
}

// final LN over (sum of P fp32 partials + bias + bf16 residual), D=128, fp32 out
__global__ __launch_bounds__(128)
void ln_part(const float* __restrict__ parts, long pstride, int P,
             const float* __restrict__ bias, const ushort_t* __restrict__ resid,
             const float* __restrict__ g, const float* __restrict__ beta,
             float* __restrict__ out)
{
    __shared__ float red[4];
    const int r = blockIdx.x, c = threadIdx.x;
    float x = bias[c] + bf2f(resid[r * 128 + c]);
    for (int p = 0; p < P; p++) x += parts[(size_t)p * pstride + (size_t)r * 128 + c];
    float s  = block_reduce(x, 0, red);
    float ss = block_reduce(x * x, 0, red);
    float mean = s * (1.f / 128.f);
    float var  = ss * (1.f / 128.f) - mean * mean;
    float inv  = rsqrtf(var + 1e-5f);
    out[(size_t)r * 128 + c] = (x - mean) * inv * g[c] + beta[c];
}

// ---------------------------------------------------------------------------
// V transpose: out[z][d][n] = in[z1*inz1 + z2*inz2 + n*ldin + d], d<128.
// ---------------------------------------------------------------------------
__global__ __launch_bounds__(256)
void transp128(const ushort_t* __restrict__ in, ushort_t* __restrict__ out,
               int ldin, long inz1, long inz2, long outz)
{
    __shared__ ushort_t T[64][136];
    const int z = blockIdx.z, z1 = z & 7, z2 = z >> 3;
    const int n0 = blockIdx.x * 64;
    const ushort_t* ip = in + (size_t)z1 * inz1 + (size_t)z2 * inz2;
    const int rr = threadIdx.x >> 2, cg = (threadIdx.x & 3) * 32;
#pragma unroll
    for (int c = 0; c < 4; c++) {
        s16x8 v = *(const s16x8*)(ip + (size_t)(n0 + rr) * ldin + cg + c * 8);
        *(s16x8*)&T[rr][cg + c * 8] = v;
    }
    __syncthreads();
    const int d = threadIdx.x >> 1, j0 = (threadIdx.x & 1) * 32;
    ushort_t* op = out + (size_t)z * outz + (size_t)d * 1024 + n0 + j0;
#pragma unroll
    for (int c = 0; c < 4; c++) {
        s16x8 v;
#pragma unroll
        for (int j = 0; j < 8; j++) v[j] = (short)T[j0 + c * 8 + j][d];
        *(s16x8*)(op + c * 8) = v;
    }
}

// ---------------------------------------------------------------------------
// Collapsed feature-attention precompute (phases 1+2 merged, single block)
// consts (floats): u@0(384) v@512(384) abcd@1024(16) wv@1088(512) c0@1600(128)
// Gb packed: bf16[2048][8]: cols 0..3 = g[m][h], col 4 = g0[m], 5..7 = 0
// ---------------------------------------------------------------------------
__global__ void precomp12(const float* __restrict__ fa_wi, const float* __restrict__ fa_bi,
                          const float* __restrict__ pl1_w, const float* __restrict__ pl1_b,
                          const float* __restrict__ fa_wo, const float* __restrict__ fa_bo,
                          float* __restrict__ consts)
{
    int j = threadIdx.x;   // 384 threads
    if (j < 384) {
        float u = 0.f, v = 0.f;
        for (int k = 0; k < 128; k++) {
            float w = fa_wi[j * 128 + k];
            u = fmaf(w, pl1_w[k], u);
            v = fmaf(w, pl1_b[k], v);
        }
        consts[j]       = u;
        consts[512 + j] = v + fa_bi[j];
    }
    __syncthreads();
    if (j < 128) {
        const float* u = consts;
        const float* v = consts + 512;
        if (j < 16) {
            int h = j >> 2, w = j & 3;
            const float* ql = (w < 2) ? u : v;
            const float* kr = ((w & 1) == 0) ? u : v;
            float acc = 0.f;
            for (int d = 0; d < 32; d++) acc += ql[h * 32 + d] * kr[128 + h * 32 + d];
            consts[1024 + j] = acc * 0.17677669529663687f;
        }
#pragma unroll
        for (int h = 0; h < 4; h++) {
            float acc = 0.f;
            for (int d = 0; d < 32; d++)
                acc = fmaf(fa_wo[j * 128 + h * 32 + d], u[256 + h * 32 + d], acc);
            consts[1088 + h * 128 + j] = acc;
        }
        float c0 = fa_bo[j];
        for (int idx = 0; idx < 128; idx++)
            c0 = fmaf(fa_wo[j * 128 + idx], v[256 + idx], c0);
        consts[1600 + j] = c0;
    }
}

__global__ void precomp3(const float* __restrict__ pl2_w, const float* __restrict__ pl2_b,
                         const float* __restrict__ consts, ushort_t* __restrict__ Gb)
{
    int m = blockIdx.x * 256 + threadIdx.x;   // 2048
    const float* wv = consts + 1088;
    const float* c0 = consts + 1600;
    float a0 = 0.f, ah[4] = {0.f, 0.f, 0.f, 0.f};
    for (int j = 0; j < 128; j++) {
        float w = pl2_w[m * 128 + j];
        ah[0] = fmaf(w, wv[0 * 128 + j], ah[0]);
        ah[1] = fmaf(w, wv[1 * 128 + j], ah[1]);
        ah[2] = fmaf(w, wv[2 * 128 + j], ah[2]);
        ah[3] = fmaf(w, wv[3 * 128 + j], ah[3]);
        a0    = fmaf(w, c0[j], a0);
    }
    ushort_t row[8];
#pragma unroll
    for (int h = 0; h < 4; h++) row[h] = f2bf(ah[h]);
    row[4] = f2bf(a0 + pl2_b[m]);
    row[5] = row[6] = row[7] = 0;
    *(uint4*)&Gb[m * 8] = *(uint4*)row;
}

// ---------------------------------------------------------------------------
// feat_t: per-token feature attention (moment softmax) -> packed T table
// Tp[(n*128+f)*8] = [t0 t1 t2 t3 1 0 0 0] bf16. 2304 blocks x 128 thr.
// ---------------------------------------------------------------------------
__global__ __launch_bounds__(128)
void feat_t(const float* __restrict__ src, const float* __restrict__ consts,
            ushort_t* __restrict__ Tp)
{
    __shared__ float sv[128];
    __shared__ float red[2];
    const int n = blockIdx.x, f = threadIdx.x;
    const float si = src[n * 128 + f];
    sv[f] = si;
    __syncthreads();

    float S1 = block_reduce(si, 0, red);
    float S2 = block_reduce(si * si, 0, red);
    float S3 = block_reduce(si * si * si, 0, red);
    float S4 = block_reduce(si * si * si * si, 0, red);
    float amax = block_reduce(fabsf(si), 1, red);

    float ph[4];
#pragma unroll
    for (int h = 0; h < 4; h++)
        ph[h] = consts[1024 + h * 4 + 0] * si + consts[1024 + h * 4 + 2];
    float pm = fmaxf(fmaxf(fabsf(ph[0]), fabsf(ph[1])), fmaxf(fabsf(ph[2]), fabsf(ph[3])));
    float pmax = block_reduce(pm, 1, red);

    ushort_t row[8];
    if (pmax * amax < 0.25f) {   // Taylor regime (block-uniform)
#pragma unroll
        for (int h = 0; h < 4; h++) {
            float p = ph[h];
            float num = fmaf(p, fmaf(p, fmaf(p, S4 * (1.f / 6.f), 0.5f * S3), S2), S1);
            float den = fmaf(p, fmaf(p, fmaf(p, S3 * (1.f / 6.f), 0.5f * S2), S1), 128.f);
            row[h] = f2bf(num / den);
        }
    } else {                     // exact fallback
        float smax = block_reduce(si, 1, red);
        float smin = -block_reduce(-si, 1, red);
#pragma unroll
        for (int h = 0; h < 4; h++) {
            float p = ph[h];
            float m = fmaxf(p * smax, p * smin);
            float l = 0.f, t = 0.f;
            for (int j = 0; j < 128; j++) {
                float e = __expf(fmaf(p, sv[j], -m));
                l += e; t = fmaf(e, sv[j], t);
            }
            row[h] = f2bf(t / l);
        }
    }
    row[4] = 0x3F80;   // 1.0 (carries g0)
    row[5] = row[6] = row[7] = 0;
    *(uint4*)&Tp[(size_t)(n * 128 + f) * 8] = *(uint4*)row;
}

// ---------------------------------------------------------------------------
// mlp_ln v3: y = relu(T@G^T)·w + residual -> LN, via 32x32x16 MFMA (K-util 50%).
// G (32 KB) + pl3_w (8 KB) LDS-staged once; barrier-free m-loop.
// 512 threads (8 waves): wave = (mh, fq): 1 f-tile(32) x 32 col-tiles(32 m).
// A: row=lane&31 (f), k=(lane>>5)*8+j -> lanes 32..63 zeroed (k>=8 dead).
// C/D: col=lane&31 (m), row=(reg&3)+8*(reg>>2)+4*(lane>>5).
// ---------------------------------------------------------------------------
__global__ __launch_bounds__(512)
void mlp_ln(const ushort_t* __restrict__ Tp, const float* __restrict__ src,
            const ushort_t* __restrict__ Gb, const float* __restrict__ pl3_w,
            const float* __restrict__ pl3_b, const float* __restrict__ pn1_g,
            const float* __restrict__ pn1_b, ushort_t* __restrict__ src1)
{
    __shared__ ushort_t Gs[2048 * 8];   // 32 KB packed G
    __shared__ float    wlds[2048];     // 8 KB pl3_w
    __shared__ float    ypart[2 * 128];
    __shared__ float    red[8];

    const int n   = blockIdx.x;
    const int tid = threadIdx.x;        // 0..511

    // ---- stage G + w once ----
#pragma unroll
    for (int p = 0; p < 4; p++) {
        int ci = tid + p * 512;
        load_lds16(Gb + (size_t)ci * 8, &Gs[ci * 8]);
    }
    load_lds16(pl3_w + tid * 4, &wlds[tid * 4]);
    __syncthreads();

    const int wave = tid >> 6, lane = tid & 63;
    const int f0   = (wave & 3) * 32;   // f-tile
    const int mh   = wave >> 2;         // m half (0..1)
    const int c32  = lane & 31, half = lane >> 5;

    // A fragment: lanes 0..31 hold k=0..7 (real), lanes 32..63 k=8..15 -> zero
    s16x8 tv = *(const s16x8*)&Tp[((size_t)n * 128 + f0 + c32) * 8];
    s16x8 af = half ? (s16x8)0 : tv;

    f32x2 part[8];
#pragma unroll
    for (int i = 0; i < 8; i++) part[i] = (f32x2)0.f;
    const f32x2 zero2 = (f32x2)0.f;

#pragma unroll 4
    for (int ct = 0; ct < 32; ct++) {
        const int m0 = mh * 1024 + ct * 32;
        s16x8 bfr = *(const s16x8*)&Gs[(m0 + c32) * 8];   // lanes 32..63 bcast
        float w = wlds[m0 + c32];
        f32x2 w2 = { w, w };
        f32x16 acc = __builtin_amdgcn_mfma_f32_32x32x16_bf16(af, bfr, (f32x16)0.f, 0, 0, 0);
        f32x2* pa = (f32x2*)&acc;
#pragma unroll
        for (int i = 0; i < 8; i++) {
            f32x2 r = __builtin_elementwise_max(pa[i], zero2);   // v_pk_max_f32
            part[i] = r * w2 + part[i];                          // v_pk_fma_f32
        }
    }

    // reduce over the 32 m-cols (lane bits 0..4; bit 5 = row-half preserved)
#pragma unroll
    for (int reg = 0; reg < 16; reg++) {
        float v = part[reg >> 1][reg & 1];
        v += __shfl_xor(v, 1);
        v += __shfl_xor(v, 2);
        v += __shfl_xor(v, 4);
        v += __shfl_xor(v, 8);
        v += __shfl_xor(v, 16);
        if (c32 == 0) {
            int row = (reg & 3) + 8 * (reg >> 2) + 4 * half;
            ypart[mh * 128 + f0 + row] = v;
        }
    }
    __syncthreads();

    float yv = 0.f;
    const int f = tid & 127;
    if (tid < 128)
        yv = ypart[f] + ypart[128 + f] + pl3_b[0] + src[n * 128 + f];
    float s  = block_reduce(yv, 0, red);
    float ss = block_reduce(yv * yv, 0, red);
    float mean = s * (1.f / 128.f);
    float var  = ss * (1.f / 128.f) - mean * mean;
    float inv  = rsqrtf(var + 1e-5f);
    if (tid < 128)
        src1[n * 128 + f] = f2bf((yv - mean) * inv * pn1_g[f] + pn1_b[f]);
}

// LN over bf16: out = LN(a [+ b]) * g + beta;  out bf16 or fp32
template<bool OUTF32>
__global__ void ln_bf16(const ushort_t* __restrict__ a, const ushort_t* __restrict__ b,
                        const ushort_t* __restrict__ post, const float* __restrict__ g,
                        const float* __restrict__ beta, void* __restrict__ out, int D)
{
    __shared__ float red[4];
    const size_t row = blockIdx.x;
    const int tid = threadIdx.x;
    const int nit = D / blockDim.x;   // <= 4
    const ushort_t* ap = a + row * D;
    const ushort_t* bp = b ? b + row * D : nullptr;
    float xr[4];
    float s = 0.f, ss = 0.f;
    for (int i = 0; i < nit; i++) {
        int idx = i * blockDim.x + tid;
        float x = bf2f(ap[idx]) + (bp ? bf2f(bp[idx]) : 0.f);
        xr[i] = x; s += x; ss = fmaf(x, x, ss);
    }
    s  = block_reduce(s, 0, red);
    ss = block_reduce(ss, 0, red);
    float mean = s / D, var = ss / D - mean * mean;
    float inv = rsqrtf(var + 1e-5f);
    const ushort_t* pp = post ? post + row * D : nullptr;
    for (int i = 0; i < nit; i++) {
        int idx = i * blockDim.x + tid;
        float v = (xr[i] - mean) * inv * g[idx] + beta[idx];
        if (pp) v += bf2f(pp[idx]);
        if (OUTF32) ((float*)out)[row * D + idx] = v;
        else        ((ushort_t*)out)[row * D + idx] = f2bf(v);
    }
}

// LN over concat(a1[0:split], Σparts+bias2 [rows>=split]) + b -> bf16, D=1024
__global__ __launch_bounds__(256)
void ln_cat2(const ushort_t* __restrict__ a1, const float* __restrict__ parts,
             long pstride, int P, const float* __restrict__ bias2, int split,
             const ushort_t* __restrict__ b, const float* __restrict__ g,
             const float* __restrict__ beta, ushort_t* __restrict__ out)
{
    __shared__ float red[4];
    const int row = blockIdx.x;
    const int tid = threadIdx.x;
    float xr[4];
    float s = 0.f, ss = 0.f;
#pragma unroll
    for (int i = 0; i < 4; i++) {
        int idx = i * 256 + tid;
        float x;
        if (row < split) {
            x = bf2f(a1[(size_t)row * 1024 + idx]);
        } else {
            int r2 = row - split;
            x = bias2[idx];
            for (int p = 0; p < P; p++)
                x += parts[(size_t)p * pstride + (size_t)r2 * 1024 + idx];
        }
        x += bf2f(b[(size_t)row * 1024 + idx]);
        xr[i] = x; s += x; ss = fmaf(x, x, ss);
    }
    s  = block_reduce(s, 0, red);
    ss = block_reduce(ss, 0, red);
    float mean = s * (1.f / 1024.f);
    float var  = ss * (1.f / 1024.f) - mean * mean;
    float inv  = rsqrtf(var + 1e-5f);
#pragma unroll
    for (int i = 0; i < 4; i++) {
        int idx = i * 256 + tid;
        out[(size_t)row * 1024 + idx] = f2bf((xr[i] - mean) * inv * g[idx] + beta[idx]);
    }
}

// row softmax in place, bf16, cols == 1024, 256 threads
__global__ __launch_bounds__(256)
void softmax_bf16(ushort_t* __restrict__ S)
{
    __shared__ float red[4];
    const size_t row = blockIdx.x;
    ushort_t* p = S + row * 1024;
    const int tid = threadIdx.x;
    uint2 u = *(const uint2*)&p[tid * 4];
    ushort_t* us = (ushort_t*)&u;
    float xr[4];
    float mx = -3.4e38f;
#pragma unroll
    for (int i = 0; i < 4; i++) { xr[i] = bf2f(us[i]); mx = fmaxf(mx, xr[i]); }
    mx = block_reduce(mx, 1, red);
    float sum = 0.f;
#pragma unroll
    for (int i = 0; i < 4; i++) { xr[i] = __expf(xr[i] - mx); sum += xr[i]; }
    sum = block_reduce(sum, 0, red);
    float inv = 1.f / sum;
#pragma unroll
    for (int i = 0; i < 4; i++) us[i] = f2bf(xr[i] * inv);
    *(uint2*)&p[tid * 4] = u;
}

// ---------------------------------------------------------------------------
// Host side
// ---------------------------------------------------------------------------
static inline void gemm_go(hipStream_t s, const ushort_t* A, const ushort_t* B,
                           const float* bias, ushort_t* C,
                           int M, int N, int K, int lda, int ldb, int ldc,
                           long sAz, long sBz, long sCz, int Z, float alpha,
                           bool relu,
                           long sA2 = 0, long sB2 = 0, long sC2 = 0, int zshift = 0,
                           int ksplit = 1, float* Cp = nullptr, long pstride = 0)
{
    dim3 g(M / 128, N / 128, Z * ksplit), b(256);
    int ksplen = K / ksplit;
    if (ksplit > 1)
        gemm_bf16<false, true ><<<g, b, 0, s>>>(A, B, nullptr, nullptr, Cp, pstride, ksplen, Z,
            M, N, K, lda, ldb, ldc, sAz, sBz, sCz, sA2, sB2, sC2, zshift, alpha);
    else if (relu)
        gemm_bf16<true,  false><<<g, b, 0, s>>>(A, B, bias, C, nullptr, 0, 0, Z,
            M, N, K, lda, ldb, ldc, sAz, sBz, sCz, sA2, sB2, sC2, zshift, alpha);
    else
        gemm_bf16<false, false><<<g, b, 0, s>>>(A, B, bias, C, nullptr, 0, 0, Z,
            M, N, K, lda, ldb, ldc, sAz, sBz, sCz, sA2, sB2, sC2, zshift, alpha);
}

extern "C" void kernel_launch(void* const* d_in, const int* in_sizes, int n_in,
                              void* d_out, int out_size, void* d_ws, size_t ws_size,
                              hipStream_t stream)
{
    const float* src   = (const float*)d_in[0];
    const float* sa_wi = (const float*)d_in[2];
    const float* sa_bi = (const float*)d_in[3];
    const float* sa_wo = (const float*)d_in[4];
    const float* sa_bo = (const float*)d_in[5];
    const float* fa_wi = (const float*)d_in[6];
    const float* fa_bi = (const float*)d_in[7];
    const float* fa_wo = (const float*)d_in[8];
    const float* fa_bo = (const float*)d_in[9];
    const float* pl1_w = (const float*)d_in[10];
    const float* pl1_b = (const float*)d_in[11];
    const float* pl2_w = (const float*)d_in[12];
    const float* pl2_b = (const float*)d_in[13];
    const float* pl3_w = (const float*)d_in[14];
    const float* pl3_b = (const float*)d_in[15];
    const float* pl4_w = (const float*)d_in[16];
    const float* pl4_b = (const float*)d_in[17];
    const float* pl5_w = (const float*)d_in[18];
    const float* pl5_b = (const float*)d_in[19];
    const float* pl6_w = (const float*)d_in[20];
    const float* pl6_b = (const float*)d_in[21];
    const float* pl7_w = (const float*)d_in[22];
    const float* pl7_b = (const float*)d_in[23];
    const float* l1_w  = (const float*)d_in[24];
    const float* l1_b  = (const float*)d_in[25];
    const float* l2_w  = (const float*)d_in[26];
    const float* l2_b  = (const float*)d_in[27];
    const float* pn1_g = (const float*)d_in[28];
    const float* pn1_b = (const float*)d_in[29];
    const float* pn2_g = (const float*)d_in[30];
    const float* pn2_b = (const float*)d_in[31];
    const float* n1_g  = (const float*)d_in[32];
    const float* n1_b  = (const float*)d_in[33];
    const float* n2_g  = (const float*)d_in[34];
    const float* n2_b  = (const float*)d_in[35];

    float* ws  = (float*)d_ws;
    float* out = (float*)d_out;

    float* CONSTS = ws;                   // 16384 floats
    ushort_t* wsb = (ushort_t*)(ws + 16384);
    ushort_t* SAWIb  = wsb + 0;           // 3145728
    ushort_t* SAWOb  = wsb + 3145728;     // 1048576
    ushort_t* PL4b   = wsb + 4194304;     // 262144
    ushort_t* PL5b   = wsb + 4456448;     // 2097152
    ushort_t* PL6b   = wsb + 6553600;     // 2097152
    ushort_t* PL7b   = wsb + 8650752;     // 2097152
    ushort_t* L1b    = wsb + 10747904;    // 2097152
    ushort_t* L2b    = wsb + 12845056;    // 262144
    ushort_t* Gbb    = wsb + 13107200;    // 65536 (packed 2048x8 used)
    ushort_t* SRC1b  = wsb + 13172736;    // 294912
    ushort_t* HBIGb  = wsb + 13467648;    // 4718592 (2304x2048; also VT scratch)
    ushort_t* SRC1_b = wsb + 18186240;    // 2359296 (2304x1024)
    ushort_t* QKVb   = wsb + 20545536;    // 7077888 (2304x3072)
    ushort_t* SBUFb  = wsb + 27623424;    // 16777216 (scores / cross / splitK partials)
    ushort_t* OBUFb  = wsb + 44400640;    // 2097152
    ushort_t* SLb    = wsb + 46497792;    // 2097152
    ushort_t* SLPb   = wsb + 48594944;    // 2097152
    ushort_t* SOb    = wsb + 50692096;    // 2359296
    ushort_t* TPb    = wsb + 53051392;    // 2359296 (packed T table)
    // total ~111 MB
    float* PARTS = (float*)SBUFb;         // fp32 split-K partials (time-shared)

    // ---- one-time weight conversion (single dispatch) ----
    {
        CvtArgs a;
        const float* srcs[8] = { sa_wi, sa_wo, pl4_w, pl5_w, pl6_w, pl7_w, l1_w, l2_w };
        ushort_t*    dsts[8] = { SAWIb, SAWOb, PL4b, PL5b, PL6b, PL7b, L1b, L2b };
        int          ns[8]   = { 3145728, 1048576, 262144, 2097152, 2097152, 2097152, 2097152, 262144 };
        int cum = 0;
        for (int i = 0; i < 8; i++) { a.src[i] = srcs[i]; a.dst[i] = dsts[i]; cum += ns[i] / 4; a.end[i] = cum; }
        cvt_all<<<(cum + 255) / 256, 256, 0, stream>>>(a);
    }

    // ---- collapsed feature-attention block ----
    precomp12<<<1, 384, 0, stream>>>(fa_wi, fa_bi, pl1_w, pl1_b, fa_wo, fa_bo, CONSTS);
    precomp3<<<8, 256, 0, stream>>>(pl2_w, pl2_b, CONSTS, Gbb);
    feat_t<<<2304, 128, 0, stream>>>(src, CONSTS, TPb);
    mlp_ln<<<2304, 512, 0, stream>>>(TPb, src, Gbb, pl3_w, pl3_b, pn1_g, pn1_b, SRC1b);

    // ---- src1_ = relu(src1@pl4^T+b)@pl5^T+b  (pl5 split-K x2) ----
    gemm_go(stream, SRC1b, PL4b, pl4_b, HBIGb, 2304, 2048, 128, 128, 128, 2048, 0, 0, 0, 1, 1.f, true);
    gemm_go(stream, HBIGb, PL5b, nullptr, nullptr, 2304, 1024, 2048, 2048, 2048, 1024, 0, 0, 0, 1, 1.f, false,
            0, 0, 0, 0, 2, PARTS, 2359296);
    sum_cvt<false><<<2304, 256, 0, stream>>>(PARTS, 2359296, 2, pl5_b, 1024, SRC1_b, 589824);

    // ---- qkv over ALL 2304 rows (rows 2048+ give cross-attn Q for free) ----
    gemm_go(stream, SRC1_b, SAWIb, sa_bi, QKVb, 2304, 3072, 1024, 1024, 1024, 3072, 0, 0, 0, 1, 1.f, false);
    const float iscale = 0.08838834764831845f;   // 1/sqrt(128)
    ushort_t* VT1 = HBIGb;
    transp128<<<dim3(16, 1, 16), 256, 0, stream>>>(QKVb + 2048, VT1, 6144, 128, 3072, 131072);
    // self-attention on rows 0..2047, z = h + 8*b
    gemm_go(stream, QKVb, QKVb + 1024, nullptr, SBUFb,
            1024, 1024, 128, 6144, 6144, 1024, 128, 128, 1048576, 16, iscale, false,
            3072, 3072, 8388608, 3);
    softmax_bf16<<<16384, 256, 0, stream>>>(SBUFb);
    gemm_go(stream, SBUFb, VT1, nullptr, OBUFb,
            1024, 128, 1024, 1024, 1024, 2048, 1048576, 131072, 128, 16, 1.f, false,
            8388608, 1048576, 1024, 3);
    // wo split-K x2 + fused reduce+LN (scores dead, PARTS = SBUF)
    gemm_go(stream, OBUFb, SAWOb, nullptr, nullptr, 2048, 1024, 1024, 1024, 1024, 1024, 0, 0, 0, 1, 1.f, false,
            0, 0, 0, 0, 2, PARTS, 2097152);
    sum_ln<<<2048, 256, 0, stream>>>(PARTS, 2097152, 2, sa_bo, SRC1_b, nullptr, pn2_g, pn2_b, SLb);

    // ---- sl_ = ln(relu(sl@pl6^T)@pl7^T, pn2) + sl ----
    gemm_go(stream, SLb, PL6b, nullptr, nullptr, 2048, 2048, 1024, 1024, 1024, 2048, 0, 0, 0, 1, 1.f, false,
            0, 0, 0, 0, 2, PARTS, 4194304);
    sum_cvt<true><<<4096, 256, 0, stream>>>(PARTS, 4194304, 2, pl6_b, 2048, HBIGb, 1048576);
    gemm_go(stream, HBIGb, PL7b, nullptr, nullptr, 2048, 1024, 2048, 2048, 2048, 1024, 0, 0, 0, 1, 1.f, false,
            0, 0, 0, 0, 2, PARTS, 2097152);
    sum_ln<<<2048, 256, 0, stream>>>(PARTS, 2097152, 2, pl7_b, nullptr, SLb, pn2_g, pn2_b, SLPb);

    // ---- cross-attention: q from qkv rows 2048+, k/v from sl_ ----
    ushort_t* KV2 = SBUFb;               // 2048x2048
    ushort_t* S2  = SBUFb + 4456448;     // 16x128x1024
    gemm_go(stream, SLPb, SAWIb + 1024 * 1024, sa_bi + 1024, KV2, 2048, 2048, 1024, 1024, 1024, 2048, 0, 0, 0, 1, 1.f, false);
    ushort_t* VT2 = HBIGb;
    transp128<<<dim3(16, 1, 16), 256, 0, stream>>>(KV2 + 1024, VT2, 4096, 128, 2048, 131072);
    gemm_go(stream, QKVb + 2048 * 3072, KV2, nullptr, S2,
            128, 1024, 128, 6144, 4096, 1024, 128, 128, 131072, 16, iscale, false,
            3072, 2048, 1048576, 3);
    softmax_bf16<<<2048, 256, 0, stream>>>(S2);
    gemm_go(stream, S2, VT2, nullptr, nullptr,
            128, 128, 1024, 1024, 1024, 2048, 131072, 131072, 128, 16, 1.f, false,
            1048576, 1048576, 1024, 3, 8, PARTS, 262144);
    sum_cvt<false><<<256, 256, 0, stream>>>(PARTS, 262144, 8, nullptr, 2048, OBUFb, 65536);
    // sr-out split-K x8; reduce folded into ln_cat2
    gemm_go(stream, OBUFb, SAWOb, nullptr, nullptr, 256, 1024, 1024, 1024, 1024, 1024, 0, 0, 0, 1, 1.f, false,
            0, 0, 0, 0, 8, PARTS, 262144);

    // ---- so = ln(concat(sl, sr) + src1_, n1)  (sr reduce fused) ----
    ln_cat2<<<2304, 256, 0, stream>>>(SLb, PARTS, 262144, 8, sa_bo, 2048, SRC1_b, n1_g, n1_b, SOb);

    // ---- ff = relu(so@l1^T)@l2^T ; out = ln(src1 + ff, n2) ----
    gemm_go(stream, SOb, L1b, nullptr, nullptr, 2304, 2048, 1024, 1024, 1024, 2048, 0, 0, 0, 1, 1.f, false,
            0, 0, 0, 0, 2, PARTS, 4718592);
    sum_cvt<true><<<4608, 256, 0, stream>>>(PARTS, 4718592, 2, l1_b, 2048, HBIGb, 1179648);
    gemm_go(stream, HBIGb, L2b, nullptr, nullptr, 2304, 128, 2048, 2048, 2048, 128, 0, 0, 0, 1, 1.f, false,
            0, 0, 0, 0, 8, PARTS, 294912);
    ln_part<<<2304, 128, 0, stream>>>(PARTS, 294912, 8, l2_b, SRC1b, n2_g, n2_b, out);
}